// Round 1
// baseline (430.711 us; speedup 1.0000x reference)
//
#include <hip/hip_runtime.h>
#include <hip/hip_bf16.h>

// WindAdaptivePooling: out[b][c] = mean(x[b][c][:,:]) * softmax(wind_weights)[wind_indices[b]]
// x: [64,1280,32,32] fp32 (contiguous HW=1024 per row), out: [64,1280] fp32.
// Memory-bound: ~335 MB read. One wave (64 lanes) per (b,c) row; float4 loads
// (16 B/lane), shfl_down wave reduction, lane 0 computes scale + stores.

#define NUM_WINDS 8
#define C_DIM 1280
#define HW 1024  // 32*32

__global__ __launch_bounds__(256) void wind_pool_kernel(
    const float* __restrict__ x,
    const int* __restrict__ wind_indices,
    const float* __restrict__ wind_weights,
    float* __restrict__ out,
    int n_rows) {
    const int gtid = blockIdx.x * blockDim.x + threadIdx.x;
    const int wave_id = gtid >> 6;   // one wave per (b,c) row
    const int lane = gtid & 63;
    if (wave_id >= n_rows) return;

    const float4* row = reinterpret_cast<const float4*>(x + (size_t)wave_id * HW);
    // 1024 floats = 256 float4; 64 lanes * 4 iters. Coalesced: lane i reads 16B at i*16.
    float4 v0 = row[lane];
    float4 v1 = row[lane + 64];
    float4 v2 = row[lane + 128];
    float4 v3 = row[lane + 192];

    float s = (v0.x + v0.y) + (v0.z + v0.w)
            + (v1.x + v1.y) + (v1.z + v1.w)
            + (v2.x + v2.y) + (v2.z + v2.w)
            + (v3.x + v3.y) + (v3.z + v3.w);

    // wave64 butterfly reduce
    #pragma unroll
    for (int off = 32; off > 0; off >>= 1)
        s += __shfl_down(s, off, 64);

    if (lane == 0) {
        const int b = wave_id / C_DIM;
        const int idx = wind_indices[b];
        // softmax over the 8 wind weights (tiny; cached)
        float w[NUM_WINDS];
        float m = -1e30f;
        #pragma unroll
        for (int i = 0; i < NUM_WINDS; ++i) {
            w[i] = wind_weights[i];
            m = fmaxf(m, w[i]);
        }
        float denom = 0.0f;
        #pragma unroll
        for (int i = 0; i < NUM_WINDS; ++i)
            denom += __expf(w[i] - m);
        const float scale = __expf(w[idx] - m) / denom;
        out[wave_id] = s * (1.0f / (float)HW) * scale;
    }
}

extern "C" void kernel_launch(void* const* d_in, const int* in_sizes, int n_in,
                              void* d_out, int out_size, void* d_ws, size_t ws_size,
                              hipStream_t stream) {
    const float* x = (const float*)d_in[0];
    const int* wind_indices = (const int*)d_in[1];
    const float* wind_weights = (const float*)d_in[2];
    float* out = (float*)d_out;

    const int n_rows = out_size;            // 64 * 1280 = 81920
    const int waves_per_block = 256 / 64;   // 4 rows per block
    const int n_blocks = (n_rows + waves_per_block - 1) / waves_per_block;

    wind_pool_kernel<<<n_blocks, 256, 0, stream>>>(x, wind_indices, wind_weights, out, n_rows);
}

// Round 4
// 406.928 us; speedup vs baseline: 1.0584x; 1.0584x over previous
//
#include <hip/hip_runtime.h>
#include <hip/hip_bf16.h>

// WindAdaptivePooling: out[b][c] = mean(x[b][c][:,:]) * softmax(wind_weights)[wind_indices[b]]
// x: [64,1280,32,32] fp32 (contiguous HW=1024 per row), out: [64,1280] fp32.
// Memory-bound: ~335 MB streaming read -> floor ~53 us @ 6.3 TB/s achievable.
// One wave per 2 rows (8 KiB): 8x float4 nontemporal loads/lane in flight,
// two interleaved shfl reductions, lane 0 computes softmax scale + stores.

#define NUM_WINDS 8
#define C_DIM 1280
#define HW 1024         // 32*32 floats per row
#define ROW_F4 256      // float4 per row

typedef float f32x4 __attribute__((ext_vector_type(4)));

__global__ __launch_bounds__(256) void wind_pool_kernel(
    const float* __restrict__ x,
    const int* __restrict__ wind_indices,
    const float* __restrict__ wind_weights,
    float* __restrict__ out,
    int n_rows) {
    const int gtid = blockIdx.x * blockDim.x + threadIdx.x;
    const int wave_id = gtid >> 6;       // one wave per 2 rows
    const int lane = gtid & 63;
    const int r0 = wave_id * 2;          // rows r0, r0+1 (same b: C_DIM is even)
    if (r0 >= n_rows) return;

    const f32x4* row0 = reinterpret_cast<const f32x4*>(x) + (size_t)r0 * ROW_F4;
    const f32x4* row1 = row0 + ROW_F4;

    // Issue all 8 loads back-to-back: contiguous 1 KiB per instruction, 8 KiB total.
    f32x4 a0 = __builtin_nontemporal_load(row0 + lane);
    f32x4 a1 = __builtin_nontemporal_load(row0 + lane + 64);
    f32x4 a2 = __builtin_nontemporal_load(row0 + lane + 128);
    f32x4 a3 = __builtin_nontemporal_load(row0 + lane + 192);
    f32x4 b0 = __builtin_nontemporal_load(row1 + lane);
    f32x4 b1 = __builtin_nontemporal_load(row1 + lane + 64);
    f32x4 b2 = __builtin_nontemporal_load(row1 + lane + 128);
    f32x4 b3 = __builtin_nontemporal_load(row1 + lane + 192);

    float s0 = (a0.x + a0.y) + (a0.z + a0.w)
             + (a1.x + a1.y) + (a1.z + a1.w)
             + (a2.x + a2.y) + (a2.z + a2.w)
             + (a3.x + a3.y) + (a3.z + a3.w);
    float s1 = (b0.x + b0.y) + (b0.z + b0.w)
             + (b1.x + b1.y) + (b1.z + b1.w)
             + (b2.x + b2.y) + (b2.z + b2.w)
             + (b3.x + b3.y) + (b3.z + b3.w);

    // wave64 butterfly reduce, two rows interleaved (ILP on the shfl chain)
    #pragma unroll
    for (int off = 32; off > 0; off >>= 1) {
        s0 += __shfl_down(s0, off, 64);
        s1 += __shfl_down(s1, off, 64);
    }

    if (lane == 0) {
        const int b = r0 / C_DIM;
        const int idx = wind_indices[b];
        float w[NUM_WINDS];
        float m = -1e30f;
        #pragma unroll
        for (int i = 0; i < NUM_WINDS; ++i) {
            w[i] = wind_weights[i];
            m = fmaxf(m, w[i]);
        }
        float denom = 0.0f;
        #pragma unroll
        for (int i = 0; i < NUM_WINDS; ++i)
            denom += __expf(w[i] - m);
        const float scale = __expf(w[idx] - m) / denom * (1.0f / (float)HW);
        out[r0] = s0 * scale;
        out[r0 + 1] = s1 * scale;
    }
}

extern "C" void kernel_launch(void* const* d_in, const int* in_sizes, int n_in,
                              void* d_out, int out_size, void* d_ws, size_t ws_size,
                              hipStream_t stream) {
    const float* x = (const float*)d_in[0];
    const int* wind_indices = (const int*)d_in[1];
    const float* wind_weights = (const float*)d_in[2];
    float* out = (float*)d_out;

    const int n_rows = out_size;                 // 64 * 1280 = 81920
    const int n_waves = n_rows / 2;              // 2 rows per wave
    const int waves_per_block = 256 / 64;        // 4 waves per block
    const int n_blocks = (n_waves + waves_per_block - 1) / waves_per_block;

    wind_pool_kernel<<<n_blocks, 256, 0, stream>>>(x, wind_indices, wind_weights, out, n_rows);
}